// Round 9
// baseline (104.522 us; speedup 1.0000x reference)
//
#include <hip/hip_runtime.h>

// ChamferLoss: x,y [4, 8192, 3] fp32 -> scalar fp32.
// out = (sum_bn min_m d2 + sum_bm min_n d2) / 32768
//
// Round 9: R5/R7/R8 all report VGPR_Count 44-52 while the sweep's live set
// is >=64 regs (48 query + 16 acc) -> compiler is parking values in AGPRs
// and shuttling via v_accvgpr_read/write (full VALU insts) = the hidden ~2x
// VALU tax that pins every Q=16 variant at 44-52us. Fix: TWO sequential
// 8-query half-sweeps (live set ~56 regs each, no AGPR traffic). Records are
// re-read from LDS (DS pipe 10->20.5us, still under the 24us VALU floor,
// co-issued). red[] no longer overlays the record buffer -> 2 barriers.
// Everything else identical to R8 (strided query ownership, conflict-free
// red[q*9+wave], qn cached in LDS, pmin atomicMin + init + sum kernels).

#define N_      8192
#define NQ      65536         // total queries (2 sides)
#define FLT_BIG 3.0e38f

__global__ void zero_out_kernel(float* out) { *out = 0.0f; }

// ---------------- init: pmin = +inf ----------------
__global__ __launch_bounds__(256) void init_kernel(unsigned int* __restrict__ pmin)
{
    int i = blockIdx.x * 256 + threadIdx.x;    // grid 64 -> 16384 uint4
    ((uint4*)pmin)[i] = make_uint4(0x7F800000u, 0x7F800000u, 0x7F800000u, 0x7F800000u);
}

// ---- 8-query sweep over 64 records (LDS broadcast, software prefetch) ----
static __device__ __forceinline__ void sweep8(
    const float4* __restrict__ rp,
    const float* qx, const float* qy, const float* qz, float* acc)
{
    float4 u = rp[0], v = rp[1];
    #pragma unroll 2
    for (int k = 0; k < 64; ++k) {
        float4 un, vn;
        if (k < 63) { un = rp[2*k+2]; vn = rp[2*k+3]; }
        #pragma unroll
        for (int j = 0; j < 8; ++j) {
            float t0 = fmaf(qx[j], u.x, fmaf(qy[j], u.y, fmaf(qz[j], u.z, u.w)));
            float t1 = fmaf(qx[j], v.x, fmaf(qy[j], v.y, fmaf(qz[j], v.z, v.w)));
            acc[j] = fminf(acc[j], fminf(t0, t1));   // v_min3_f32
        }
        u = un; v = vn;
    }
}

// ---------------- main ----------------
// 512 blocks x 512 thr. blk = {dir[1], batch[2], qg[3], seg[3]}.
// Block: 1024 queries (two passes of 8/lane, strided q = lane + 64j),
// 512 opposite records (1024 points) staged in LDS.
// Wave w sweeps records [w*64, w*64+64) twice (pass A, pass B).

__global__ __launch_bounds__(512, 4) void chamfer_kernel(
    const float* __restrict__ xraw, const float* __restrict__ yraw,
    unsigned int* __restrict__ pmin)
{
    // 56 KB: rec [0,4096) floats, red [4096,13312) (red[q*9+w]), qn [13312,14336)
    __shared__ float lds[14336];
    float4* rec4 = (float4*)lds;               // 512 records x 2 float4
    float*  red  = lds + 4096;
    float*  qn   = lds + 13312;

    const int tid  = threadIdx.x;
    const int lane = tid & 63;
    const int wave = __builtin_amdgcn_readfirstlane(tid >> 6);
    const int blk  = blockIdx.x;               // 0..511
    const int dir   = blk >> 8;                // 0: x-queries vs y, 1: y vs x
    const int batch = (blk >> 6) & 3;
    const int qg    = (blk >> 3) & 7;          // query group (1024 q)
    const int seg   = blk & 7;                 // record segment (512 recs)

    const float* qraw = dir ? yraw : xraw;
    const float* oraw = dir ? xraw : yraw;

    // ---- stage: 512 records {x0,y0,z0,w0}{x1,y1,z1,w1}, 1/thread ----
    {
        int r = tid;                           // 0..511
        const float2* p2 = (const float2*)(oraw + ((size_t)batch * N_ + seg * 1024 + 2 * r) * 3);
        float2 a = p2[0], b = p2[1], c = p2[2];   // x0,y0 | z0,x1 | y1,z1
        float w0 = fmaf(a.x, a.x, fmaf(a.y, a.y, b.x * b.x));
        float w1 = fmaf(b.y, b.y, fmaf(c.x, c.x, c.y * c.y));
        rec4[2*r]   = make_float4(a.x, a.y, b.x, w0);
        rec4[2*r+1] = make_float4(b.y, c.x, c.y, w1);
    }

    const int qbase = batch * N_ + qg * 1024;
    const float4* rp = rec4 + wave * 128;      // this wave's 64 records

    float qx[8], qy[8], qz[8], accA[8], accB[8];

    // ---- pass A queries: j = 0..7, q = lane + 64j (coalesced b32) ----
    #pragma unroll
    for (int j = 0; j < 8; ++j) {
        int q = lane + 64 * j;
        const float* qp = qraw + (size_t)(qbase + q) * 3;
        float ax = qp[0], ay = qp[1], az = qp[2];
        qx[j] = -2.0f * ax; qy[j] = -2.0f * ay; qz[j] = -2.0f * az;
        if (wave == 0) qn[q] = fmaf(ax, ax, fmaf(ay, ay, az * az));
        accA[j] = FLT_BIG;
    }
    __syncthreads();                           // records staged

    sweep8(rp, qx, qy, qz, accA);

    // ---- pass B queries: j = 8..15 (qn area disjoint from records) ----
    #pragma unroll
    for (int j = 0; j < 8; ++j) {
        int q = lane + 64 * (j + 8);
        const float* qp = qraw + (size_t)(qbase + q) * 3;
        float ax = qp[0], ay = qp[1], az = qp[2];
        qx[j] = -2.0f * ax; qy[j] = -2.0f * ay; qz[j] = -2.0f * az;
        if (wave == 0) qn[q] = fmaf(ax, ax, fmaf(ay, ay, az * az));
        accB[j] = FLT_BIG;
    }
    sweep8(rp, qx, qy, qz, accB);

    // ---- write wave partials: red[q*9 + wave] (2-way bank alias = free) ----
    #pragma unroll
    for (int j = 0; j < 8; ++j) {
        red[(lane + 64 * j) * 9 + wave]       = accA[j];
        red[(lane + 64 * (j + 8)) * 9 + wave] = accB[j];
    }
    __syncthreads();

    // ---- combine: thread t owns queries t and t+512 ----
    #pragma unroll
    for (int r2 = 0; r2 < 2; ++r2) {
        int q = r2 * 512 + tid;
        float m = red[q * 9];
        #pragma unroll
        for (int w = 1; w < 8; ++w) m = fminf(m, red[q * 9 + w]);
        float d2 = fmaxf(0.0f, qn[q] + m);     // relu commutes with min
        atomicMin(&pmin[dir * 32768 + qbase + q], __float_as_uint(d2));
    }
}

// ---------------- sum: single block, deterministic ----------------
__global__ __launch_bounds__(1024) void sum_kernel(
    const unsigned int* __restrict__ pmin, float* __restrict__ out)
{
    __shared__ float sred[16];
    const int tid = threadIdx.x;
    const float4* pv = (const float4*)pmin;    // bits are valid non-neg floats
    float s = 0.0f;
    #pragma unroll
    for (int k = 0; k < 16; ++k) {             // 16384 float4 / 1024 threads
        float4 v = pv[k * 1024 + tid];
        s += v.x + v.y + v.z + v.w;
    }
    #pragma unroll
    for (int off = 32; off > 0; off >>= 1) s += __shfl_xor(s, off);
    if ((tid & 63) == 0) sred[tid >> 6] = s;
    __syncthreads();
    if (tid < 16) {
        float v = sred[tid];
        #pragma unroll
        for (int off = 8; off > 0; off >>= 1) v += __shfl_xor(v, off);
        if (tid == 0) *out = v * (1.0f / 32768.0f);
    }
}

// ---------------- fallback (ws too small): round-1 kernel ----------------
__global__ __launch_bounds__(1024) void chamfer_raw_kernel(
    const float* __restrict__ xraw, const float* __restrict__ yraw,
    float* __restrict__ out)
{
    __shared__ float4 red4[16][64];
    const int tid  = threadIdx.x;
    const int wave = tid >> 6;
    const int lane = tid & 63;
    const int blk  = blockIdx.x;
    const bool xdir = (blk < 128);
    const int b    = (blk & 127) >> 5;
    const int qofs = (blk & 31) << 8;
    const float* qraw = xdir ? xraw : yraw;
    const float* oraw = xdir ? yraw : xraw;
    float qx0[4], qx1[4], qx2[4], acc[4];
    #pragma unroll
    for (int q = 0; q < 4; ++q) {
        int gq = b * N_ + qofs + lane*4 + q;
        qx0[q] = qraw[gq*3+0]; qx1[q] = qraw[gq*3+1]; qx2[q] = qraw[gq*3+2];
        acc[q] = FLT_BIG;
    }
    const float* opp = oraw + (size_t)(b * N_ + wave * 512) * 3;
    #pragma unroll 4
    for (int k = 0; k < 512; ++k) {
        float p0 = opp[k*3+0], p1 = opp[k*3+1], p2 = opp[k*3+2];
        float w  = fmaf(p0, p0, fmaf(p1, p1, p2*p2));
        #pragma unroll
        for (int q = 0; q < 4; ++q) {
            float dot = qx0[q]*p0 + qx1[q]*p1 + qx2[q]*p2;
            acc[q] = fminf(acc[q], fmaf(-2.0f, dot, w));
        }
    }
    red4[wave][lane] = make_float4(acc[0], acc[1], acc[2], acc[3]);
    __syncthreads();
    if (tid < 256) {
        const float* red = (const float*)red4;
        float m = red[tid];
        #pragma unroll
        for (int w = 1; w < 16; ++w) m = fminf(m, red[w*256 + tid]);
        int gq = b * N_ + qofs + tid;
        float ax = qraw[gq*3+0], ay = qraw[gq*3+1], az = qraw[gq*3+2];
        float d2 = fmaxf(0.0f, fmaf(ax,ax,fmaf(ay,ay,az*az)) + m);
        #pragma unroll
        for (int off = 32; off > 0; off >>= 1) d2 += __shfl_xor(d2, off);
        if ((tid & 63) == 0) atomicAdd(out, d2 * (1.0f / 32768.0f));
    }
}

extern "C" void kernel_launch(void* const* d_in, const int* in_sizes, int n_in,
                              void* d_out, int out_size, void* d_ws, size_t ws_size,
                              hipStream_t stream)
{
    const float* x = (const float*)d_in[0];
    const float* y = (const float*)d_in[1];
    float* out = (float*)d_out;

    const size_t need = (size_t)NQ * 4;        // 256 KB pmin
    if (ws_size >= need) {
        unsigned int* pmin = (unsigned int*)d_ws;
        init_kernel<<<64, 256, 0, stream>>>(pmin);
        chamfer_kernel<<<512, 512, 0, stream>>>(x, y, pmin);
        sum_kernel<<<1, 1024, 0, stream>>>(pmin, out);
    } else {
        zero_out_kernel<<<1, 1, 0, stream>>>(out);
        chamfer_raw_kernel<<<256, 1024, 0, stream>>>(x, y, out);
    }
}